// Round 3
// baseline (341.543 us; speedup 1.0000x reference)
//
#include <hip/hip_runtime.h>
#include <math.h>

#define NV 100000
#define NK 64
#define NF 16
#define EPS_W 1e-4f
#define NGRP (NV / 4)        // 25000 groups of 4 vertices
#define GRID 625             // 625 blocks * 4 waves = 2500 waves * 10 groups = 25000

typedef __attribute__((ext_vector_type(8))) short bf16x8;
typedef __attribute__((ext_vector_type(4))) float f32x4;

__device__ __forceinline__ unsigned short bfu(float x) {
    return __builtin_bit_cast(unsigned short, (__bf16)x);   // HW RNE cvt
}
__device__ __forceinline__ unsigned int pk2(float lo, float hi) {
    return (unsigned int)bfu(lo) | ((unsigned int)bfu(hi) << 16);
}
__device__ __forceinline__ float eluf(float x) {
    return x > 0.f ? x : __expf(x) - 1.f;
}

// hbuf fragment helpers (round-2 verified; XOR swizzle keeps conflicts <=2-way)
__device__ __forceinline__ bf16x8 rdfrag(const short* hb, int c, int g, int kc) {
    int boff = ((kc << 6) + (g << 4)) ^ ((c & 7) << 4);
    return *(const bf16x8*)(hb + c * 64 + (boff >> 1));
}
__device__ __forceinline__ void wrH(short* hb, int c, int g, int t,
                                    unsigned int p01, unsigned int p23) {
    int boff = ((t << 5) + (g << 3)) ^ ((c & 7) << 4);
    uint2 val; val.x = p01; val.y = p23;
    *(uint2*)(hb + c * 64 + (boff >> 1)) = val;
}

// D layout: col=lane&15, row=4*(lane>>4)+reg.  A/B: row/col=lane&15, k=8*(lane>>4)+i.
__launch_bounds__(256, 3)
__global__ void fused_kernel(const float* __restrict__ coords,
                             const float* __restrict__ distsq,
                             const float* __restrict__ feats,
                             const int*   __restrict__ nidx,
                             const float* __restrict__ W0, const float* __restrict__ b0,
                             const float* __restrict__ W1, const float* __restrict__ b1,
                             const float* __restrict__ W2, const float* __restrict__ b2,
                             const float* __restrict__ W3, const float* __restrict__ b3,
                             float* __restrict__ out)
{
    // all LDS regions are PER-WAVE (no block barriers in the main loop)
    __shared__ float sEW[4][4][64];
    __shared__ int   sIX[4][4][64];
    __shared__ __align__(16) short rowbuf[4][64 * 24];  // [wave][row][24 shorts = 48B]
    __shared__ __align__(16) short hbuf[4][16 * 64];

    const int tid  = threadIdx.x;
    const int wid  = tid >> 6;
    const int lane = tid & 63;
    const int c = lane & 15;     // feature f  / MFMA col / out-dim row
    const int g = lane >> 4;     // cov vertex-in-group / MFMA k-group
    short* hb = &hbuf[wid][0];
    short* rb = &rowbuf[wid][0];

    union U8 { short s[8]; bf16x8 v; };

    // ---- one-time per-wave weight fragments ----
    bf16x8 w0f[4], w1f[8], w2f[8], w3f[2];
    #pragma unroll
    for (int t = 0; t < 4; ++t) {
        U8 u;
        #pragma unroll
        for (int i = 0; i < 8; ++i) {
            int k = 8 * g + i;
            float val = 0.f;
            if (k < 9)       val = W0[k * 64 + 16 * t + c];
            else if (k == 9) val = b0[16 * t + c];          // bias via dim-9 = 1.0
            u.s[i] = (short)bfu(val);
        }
        w0f[t] = u.v;
    }
    #pragma unroll
    for (int t = 0; t < 4; ++t) {
        #pragma unroll
        for (int kc = 0; kc < 2; ++kc) {
            U8 u1, u2;
            #pragma unroll
            for (int i = 0; i < 8; ++i) {
                int k = 32 * kc + 8 * g + i;
                u1.s[i] = (short)bfu(W1[k * 64 + 16 * t + c]);
                u2.s[i] = (short)bfu(W2[k * 64 + 16 * t + c]);
            }
            w1f[2 * t + kc] = u1.v;
            w2f[2 * t + kc] = u2.v;
        }
    }
    #pragma unroll
    for (int kc = 0; kc < 2; ++kc) {
        U8 u;
        #pragma unroll
        for (int i = 0; i < 8; ++i) {
            int k = 32 * kc + 8 * g + i;
            u.s[i] = (short)bfu(c < 9 ? W3[k * 9 + c] : 0.f);
        }
        w3f[kc] = u.v;
    }

    float b1v[16], b2v[16], b3v[4];
    #pragma unroll
    for (int t = 0; t < 4; ++t)
        #pragma unroll
        for (int r = 0; r < 4; ++r) {
            b1v[4 * t + r] = b1[16 * t + 4 * g + r];
            b2v[4 * t + r] = b2[16 * t + 4 * g + r];
        }
    #pragma unroll
    for (int r = 0; r < 4; ++r)
        b3v[r] = (4 * g + r < 9) ? b3[4 * g + r] : 0.f;

    // ---- grid-stride over 4-vertex groups; wave fully owns a group ----
    for (int grp = blockIdx.x * 4 + wid; grp < NGRP; grp += GRID * 4) {
        const int v = grp * 4 + g;   // this lane's cov vertex (role: gv=g, f=c)

        // stage exp(-10 d^2) and idx: each lane covers 4 k's of its vertex
        {
            const size_t base = (size_t)v * NK + 4 * c;
            float4 d4 = *(const float4*)(distsq + base);
            int4   i4 = *(const int4*)(nidx + base);
            sEW[wid][g][4 * c + 0] = __expf(-10.f * d4.x);
            sEW[wid][g][4 * c + 1] = __expf(-10.f * d4.y);
            sEW[wid][g][4 * c + 2] = __expf(-10.f * d4.z);
            sEW[wid][g][4 * c + 3] = __expf(-10.f * d4.w);
            sIX[wid][g][4 * c + 0] = i4.x; sIX[wid][g][4 * c + 1] = i4.y;
            sIX[wid][g][4 * c + 2] = i4.z; sIX[wid][g][4 * c + 3] = i4.w;
        }
        __asm__ volatile("s_waitcnt lgkmcnt(0)" ::: "memory");  // per-wave visibility

        // ---- covariance for row (v, f=c) ----
        float s = 0.f, m0 = 0.f, m1 = 0.f, m2 = 0.f;
        float q00 = 0.f, q01 = 0.f, q02 = 0.f, q11 = 0.f, q12 = 0.f, q22 = 0.f;
        #pragma unroll 4
        for (int k = 0; k < NK; ++k) {
            int   idx = sIX[wid][g][k];
            float ew  = sEW[wid][g][k];
            float w   = feats[(size_t)idx * NF + c] * ew;
            float x = coords[(size_t)idx * 3 + 0];
            float y = coords[(size_t)idx * 3 + 1];
            float z = coords[(size_t)idx * 3 + 2];
            s += w;
            m0 = fmaf(w, x, m0); m1 = fmaf(w, y, m1); m2 = fmaf(w, z, m2);
            float wx = w * x, wy = w * y, wz = w * z;
            q00 = fmaf(wx, x, q00); q01 = fmaf(wx, y, q01); q02 = fmaf(wx, z, q02);
            q11 = fmaf(wy, y, q11); q12 = fmaf(wy, z, q12);
            q22 = fmaf(wz, z, q22);
        }
        float inv = 1.f / (s + EPS_W);
        float mu0 = m0 * inv, mu1 = m1 * inv, mu2 = m2 * inv;
        float c00 = fmaf(-mu0, mu0, q00 * inv);
        float c01 = fmaf(-mu0, mu1, q01 * inv);
        float c02 = fmaf(-mu0, mu2, q02 * inv);
        float c11 = fmaf(-mu1, mu1, q11 * inv);
        float c12 = fmaf(-mu1, mu2, q12 * inv);
        float c22 = fmaf(-mu2, mu2, q22 * inv);

        // pack row [c00 c01 c02 c01 c11 c12 c02 c12 c22 1 | 0...] to rowbuf
        {
            uint4 lo, hi;
            lo.x = pk2(c00, c01);
            lo.y = pk2(c02, c01);
            lo.z = pk2(c11, c12);
            lo.w = pk2(c02, c12);
            hi.x = pk2(c22, 1.0f);
            hi.y = 0u; hi.z = 0u; hi.w = 0u;
            uint4* dst = (uint4*)(rb + lane * 24);   // 48B stride: 2-way banks, 16B aligned
            dst[0] = lo;
            dst[1] = hi;
        }
        __asm__ volatile("s_waitcnt lgkmcnt(0)" ::: "memory");

        // ---- MFMA MLP over the wave's 4 vertices ----
        #pragma unroll 1
        for (int vv = 0; vv < 4; ++vv) {
            f32x4 a[4];
            // layer 0: B = cov rows from rowbuf (k 16-31 dup'd, A zero there)
            {
                bf16x8 bin = *(const bf16x8*)(rb + (16 * vv + c) * 24 + ((g & 1) << 3));
                #pragma unroll
                for (int t = 0; t < 4; ++t) {
                    f32x4 z4 = {0.f, 0.f, 0.f, 0.f};
                    a[t] = __builtin_amdgcn_mfma_f32_16x16x32_bf16(w0f[t], bin, z4, 0, 0, 0);
                }
                #pragma unroll
                for (int t = 0; t < 4; ++t)
                    wrH(hb, c, g, t, pk2(eluf(a[t][0]), eluf(a[t][1])),
                                     pk2(eluf(a[t][2]), eluf(a[t][3])));
            }
            // layer 1
            {
                bf16x8 h0 = rdfrag(hb, c, g, 0);
                bf16x8 h1 = rdfrag(hb, c, g, 1);
                #pragma unroll
                for (int t = 0; t < 4; ++t) {
                    f32x4 acc = { b1v[4*t+0], b1v[4*t+1], b1v[4*t+2], b1v[4*t+3] };
                    acc = __builtin_amdgcn_mfma_f32_16x16x32_bf16(w1f[2*t+0], h0, acc, 0, 0, 0);
                    acc = __builtin_amdgcn_mfma_f32_16x16x32_bf16(w1f[2*t+1], h1, acc, 0, 0, 0);
                    a[t] = acc;
                }
                #pragma unroll
                for (int t = 0; t < 4; ++t)
                    wrH(hb, c, g, t, pk2(eluf(a[t][0]), eluf(a[t][1])),
                                     pk2(eluf(a[t][2]), eluf(a[t][3])));
            }
            // layer 2
            {
                bf16x8 h0 = rdfrag(hb, c, g, 0);
                bf16x8 h1 = rdfrag(hb, c, g, 1);
                #pragma unroll
                for (int t = 0; t < 4; ++t) {
                    f32x4 acc = { b2v[4*t+0], b2v[4*t+1], b2v[4*t+2], b2v[4*t+3] };
                    acc = __builtin_amdgcn_mfma_f32_16x16x32_bf16(w2f[2*t+0], h0, acc, 0, 0, 0);
                    acc = __builtin_amdgcn_mfma_f32_16x16x32_bf16(w2f[2*t+1], h1, acc, 0, 0, 0);
                    a[t] = acc;
                }
                #pragma unroll
                for (int t = 0; t < 4; ++t)
                    wrH(hb, c, g, t, pk2(eluf(a[t][0]), eluf(a[t][1])),
                                     pk2(eluf(a[t][2]), eluf(a[t][3])));
            }
            // layer 3: 64 -> 9
            {
                bf16x8 h0 = rdfrag(hb, c, g, 0);
                bf16x8 h1 = rdfrag(hb, c, g, 1);
                f32x4 acc = { b3v[0], b3v[1], b3v[2], b3v[3] };
                acc = __builtin_amdgcn_mfma_f32_16x16x32_bf16(w3f[0], h0, acc, 0, 0, 0);
                acc = __builtin_amdgcn_mfma_f32_16x16x32_bf16(w3f[1], h1, acc, 0, 0, 0);
                float* op = out + (size_t)((grp * 4 + vv) * 16 + c) * 9 + (g << 2);
                if (g < 2) {
                    op[0] = eluf(acc[0]); op[1] = eluf(acc[1]);
                    op[2] = eluf(acc[2]); op[3] = eluf(acc[3]);
                } else if (g == 2) {
                    op[0] = eluf(acc[0]);   // dim 8
                }
            }
        }
    }
}

extern "C" void kernel_launch(void* const* d_in, const int* in_sizes, int n_in,
                              void* d_out, int out_size, void* d_ws, size_t ws_size,
                              hipStream_t stream) {
    (void)in_sizes; (void)n_in; (void)out_size; (void)d_ws; (void)ws_size;
    const float* coords = (const float*)d_in[0];
    const float* distsq = (const float*)d_in[1];
    const float* feats  = (const float*)d_in[2];
    const int*   nidx   = (const int*)d_in[3];
    const float* W0 = (const float*)d_in[4];
    const float* b0 = (const float*)d_in[5];
    const float* W1 = (const float*)d_in[6];
    const float* b1 = (const float*)d_in[7];
    const float* W2 = (const float*)d_in[8];
    const float* b2 = (const float*)d_in[9];
    const float* W3 = (const float*)d_in[10];
    const float* b3 = (const float*)d_in[11];
    float* out = (float*)d_out;

    hipLaunchKernelGGL(fused_kernel, dim3(GRID), dim3(256), 0, stream,
                       coords, distsq, feats, nidx,
                       W0, b0, W1, b1, W2, b2, W3, b3, out);
}

// Round 4
// 236.947 us; speedup vs baseline: 1.4414x; 1.4414x over previous
//
#include <hip/hip_runtime.h>
#include <math.h>

#define NV 100000
#define NK 64
#define NF 16
#define EPS_W 1e-4f
#define WS_NEED ((size_t)NV * 16 * 32)   // 51.2 MB: [V*F=1.6M rows][16 bf16]
#define ZSTRIDE 776                      // 64*12 + 8 pad floats per vertex plane

typedef __attribute__((ext_vector_type(8))) short bf16x8;
typedef __attribute__((ext_vector_type(4))) float f32x4;

__device__ __forceinline__ unsigned short bfu(float x) {
    return __builtin_bit_cast(unsigned short, (__bf16)x);   // HW RNE cvt
}
__device__ __forceinline__ unsigned int pk2(float lo, float hi) {
    return (unsigned int)bfu(lo) | ((unsigned int)bfu(hi) << 16);
}
__device__ __forceinline__ float eluf(float x) {
    return x > 0.f ? x : __expf(x) - 1.f;
}

// ---------------------------------------------------------------------------
// Kernel A (cov2): per-(v,k) z-records staged in LDS once, then each (v,f)
// thread does 10 FMAs + 1 feats gather per neighbour.
//   z = ew * [xx,xy,xz,yy,yz,zz,x,y,z,1], plus idx bits, pad. 48B record.
// Output row (bf16x16): [c00 c01 c02 c01 c11 c12 c02 c12 c22 1.0 0...]
// ---------------------------------------------------------------------------
__launch_bounds__(256)
__global__ void cov2_kernel(const float* __restrict__ coords,
                            const float* __restrict__ distsq,
                            const float* __restrict__ feats,
                            const int*   __restrict__ nidx,
                            unsigned char* __restrict__ ws)
{
    __shared__ __align__(16) float sZ[16 * ZSTRIDE];   // 49.7 KB

    const int tid = threadIdx.x;

    // ---- staging: 1024 (gv,k) tasks, 4 per thread ----
    #pragma unroll
    for (int r = 0; r < 4; ++r) {
        int t  = tid + r * 256;
        int gv = t >> 6, k = t & 63;
        int v  = blockIdx.x * 16 + gv;
        float d  = distsq[(size_t)v * NK + k];
        int  idx = nidx[(size_t)v * NK + k];
        float ew = __expf(-10.f * d);
        const float* cp = coords + (size_t)idx * 3;
        float x = cp[0], y = cp[1], z = cp[2];
        float* zr = sZ + gv * ZSTRIDE + k * 12;
        float4 z0 = { ew * x * x, ew * x * y, ew * x * z, ew * y * y };
        float4 z1 = { ew * y * z, ew * z * z, ew * x,     ew * y     };
        float4 z2 = { ew * z,     ew,         __int_as_float(idx), 0.f };
        *(float4*)(zr + 0) = z0;
        *(float4*)(zr + 4) = z1;
        *(float4*)(zr + 8) = z2;
    }
    __syncthreads();

    // ---- main: thread = (gv, f) ----
    const int gv = tid >> 4, f = tid & 15;
    const int v  = blockIdx.x * 16 + gv;
    const float* zb = sZ + gv * ZSTRIDE;

    float a0=0.f,a1=0.f,a2=0.f,a3=0.f,a4=0.f,a5=0.f,a6=0.f,a7=0.f,a8=0.f,a9=0.f;

    #pragma unroll 4
    for (int k = 0; k < NK; ++k) {
        float4 z0 = *(const float4*)(zb + k * 12 + 0);
        float4 z1 = *(const float4*)(zb + k * 12 + 4);
        float4 z2 = *(const float4*)(zb + k * 12 + 8);
        int   idx = __float_as_int(z2.z);
        float ft  = feats[(size_t)idx * NF + f];
        a0 = fmaf(ft, z0.x, a0); a1 = fmaf(ft, z0.y, a1);
        a2 = fmaf(ft, z0.z, a2); a3 = fmaf(ft, z0.w, a3);
        a4 = fmaf(ft, z1.x, a4); a5 = fmaf(ft, z1.y, a5);
        a6 = fmaf(ft, z1.z, a6); a7 = fmaf(ft, z1.w, a7);
        a8 = fmaf(ft, z2.x, a8); a9 = fmaf(ft, z2.y, a9);
    }

    float inv = 1.f / (a9 + EPS_W);
    float mu0 = a6 * inv, mu1 = a7 * inv, mu2 = a8 * inv;
    float c00 = fmaf(-mu0, mu0, a0 * inv);
    float c01 = fmaf(-mu0, mu1, a1 * inv);
    float c02 = fmaf(-mu0, mu2, a2 * inv);
    float c11 = fmaf(-mu1, mu1, a3 * inv);
    float c12 = fmaf(-mu1, mu2, a4 * inv);
    float c22 = fmaf(-mu2, mu2, a5 * inv);

    uint4 lo, hi;
    lo.x = pk2(c00, c01);
    lo.y = pk2(c02, c01);
    lo.z = pk2(c11, c12);
    lo.w = pk2(c02, c12);
    hi.x = pk2(c22, 1.0f);
    hi.y = 0u; hi.z = 0u; hi.w = 0u;

    uint4* dst = (uint4*)(ws + ((size_t)v * 16 + f) * 32);
    dst[0] = lo;
    dst[1] = hi;
}

// ---------------------------------------------------------------------------
// Kernel B: MFMA MLP (round-2 verified structure, HW bf16 cvt for packing).
// One wave = one vertex tile (16 rows). A = W^T fragments in VGPRs; B =
// activations via per-wave LDS with XOR swizzle.
// D layout: col=lane&15, row=4*(lane>>4)+reg.  A/B: row/col=lane&15, k=8*(lane>>4)+i.
// ---------------------------------------------------------------------------
__device__ __forceinline__ bf16x8 rdfrag(const short* hb, int c, int g, int kc) {
    int boff = ((kc << 6) + (g << 4)) ^ ((c & 7) << 4);
    return *(const bf16x8*)(hb + c * 64 + (boff >> 1));
}
__device__ __forceinline__ void wrH(short* hb, int c, int g, int t,
                                    unsigned int p01, unsigned int p23) {
    int boff = ((t << 5) + (g << 3)) ^ ((c & 7) << 4);
    uint2 val; val.x = p01; val.y = p23;
    *(uint2*)(hb + c * 64 + (boff >> 1)) = val;
}

__launch_bounds__(256, 2)
__global__ void mlp_kernel(const unsigned char* __restrict__ ws,
                           const float* __restrict__ W0, const float* __restrict__ b0,
                           const float* __restrict__ W1, const float* __restrict__ b1,
                           const float* __restrict__ W2, const float* __restrict__ b2,
                           const float* __restrict__ W3, const float* __restrict__ b3,
                           float* __restrict__ out)
{
    __shared__ __align__(16) short hbuf[4][16 * 64];
    const int tid  = threadIdx.x;
    const int wid  = tid >> 6;
    const int lane = tid & 63;
    const int c    = lane & 15;
    const int g    = lane >> 4;
    short* hb = &hbuf[wid][0];

    union U8 { short s[8]; bf16x8 v; };

    // ---- weight fragments (one-time, per wave) ----
    bf16x8 w0f[4], w1f[8], w2f[8], w3f[2];
    #pragma unroll
    for (int t = 0; t < 4; ++t) {
        U8 u;
        #pragma unroll
        for (int i = 0; i < 8; ++i) {
            int k = 8 * g + i;
            float val = 0.f;
            if (k < 9)       val = W0[k * 64 + 16 * t + c];
            else if (k == 9) val = b0[16 * t + c];       // bias via dim-9 = 1.0
            u.s[i] = (short)bfu(val);
        }
        w0f[t] = u.v;
    }
    #pragma unroll
    for (int t = 0; t < 4; ++t) {
        #pragma unroll
        for (int kc = 0; kc < 2; ++kc) {
            U8 u1, u2;
            #pragma unroll
            for (int i = 0; i < 8; ++i) {
                int k = 32 * kc + 8 * g + i;
                u1.s[i] = (short)bfu(W1[k * 64 + 16 * t + c]);
                u2.s[i] = (short)bfu(W2[k * 64 + 16 * t + c]);
            }
            w1f[2 * t + kc] = u1.v;
            w2f[2 * t + kc] = u2.v;
        }
    }
    #pragma unroll
    for (int kc = 0; kc < 2; ++kc) {
        U8 u;
        #pragma unroll
        for (int i = 0; i < 8; ++i) {
            int k = 32 * kc + 8 * g + i;
            u.s[i] = (short)bfu(c < 9 ? W3[k * 9 + c] : 0.f);
        }
        w3f[kc] = u.v;
    }

    float b1v[16], b2v[16], b3v[4];
    #pragma unroll
    for (int t = 0; t < 4; ++t)
        #pragma unroll
        for (int r = 0; r < 4; ++r) {
            b1v[4 * t + r] = b1[16 * t + 4 * g + r];
            b2v[4 * t + r] = b2[16 * t + 4 * g + r];
        }
    #pragma unroll
    for (int r = 0; r < 4; ++r)
        b3v[r] = (4 * g + r < 9) ? b3[4 * g + r] : 0.f;

    // ---- tile loop: tile = vertex ----
    const int stride = gridDim.x * 4;
    for (int t0 = blockIdx.x * 4 + wid; t0 < NV; t0 += stride) {
        f32x4 a[4];
        // layer 0: B from ws cov rows (K slots 16-31 duplicate 0-15; A zero there)
        {
            union { uint4 q; bf16x8 v; } bin;
            bin.q = *(const uint4*)(ws + (size_t)t0 * 512 + (c << 5) + ((g & 1) << 4));
            #pragma unroll
            for (int t = 0; t < 4; ++t) {
                f32x4 z4 = {0.f, 0.f, 0.f, 0.f};
                a[t] = __builtin_amdgcn_mfma_f32_16x16x32_bf16(w0f[t], bin.v, z4, 0, 0, 0);
            }
            #pragma unroll
            for (int t = 0; t < 4; ++t)
                wrH(hb, c, g, t, pk2(eluf(a[t][0]), eluf(a[t][1])),
                                 pk2(eluf(a[t][2]), eluf(a[t][3])));
        }
        // layer 1
        {
            bf16x8 h0 = rdfrag(hb, c, g, 0);
            bf16x8 h1 = rdfrag(hb, c, g, 1);
            #pragma unroll
            for (int t = 0; t < 4; ++t) {
                f32x4 acc = { b1v[4*t+0], b1v[4*t+1], b1v[4*t+2], b1v[4*t+3] };
                acc = __builtin_amdgcn_mfma_f32_16x16x32_bf16(w1f[2*t+0], h0, acc, 0, 0, 0);
                acc = __builtin_amdgcn_mfma_f32_16x16x32_bf16(w1f[2*t+1], h1, acc, 0, 0, 0);
                a[t] = acc;
            }
            #pragma unroll
            for (int t = 0; t < 4; ++t)
                wrH(hb, c, g, t, pk2(eluf(a[t][0]), eluf(a[t][1])),
                                 pk2(eluf(a[t][2]), eluf(a[t][3])));
        }
        // layer 2
        {
            bf16x8 h0 = rdfrag(hb, c, g, 0);
            bf16x8 h1 = rdfrag(hb, c, g, 1);
            #pragma unroll
            for (int t = 0; t < 4; ++t) {
                f32x4 acc = { b2v[4*t+0], b2v[4*t+1], b2v[4*t+2], b2v[4*t+3] };
                acc = __builtin_amdgcn_mfma_f32_16x16x32_bf16(w2f[2*t+0], h0, acc, 0, 0, 0);
                acc = __builtin_amdgcn_mfma_f32_16x16x32_bf16(w2f[2*t+1], h1, acc, 0, 0, 0);
                a[t] = acc;
            }
            #pragma unroll
            for (int t = 0; t < 4; ++t)
                wrH(hb, c, g, t, pk2(eluf(a[t][0]), eluf(a[t][1])),
                                 pk2(eluf(a[t][2]), eluf(a[t][3])));
        }
        // layer 3: 64 -> 9
        {
            bf16x8 h0 = rdfrag(hb, c, g, 0);
            bf16x8 h1 = rdfrag(hb, c, g, 1);
            f32x4 acc = { b3v[0], b3v[1], b3v[2], b3v[3] };
            acc = __builtin_amdgcn_mfma_f32_16x16x32_bf16(w3f[0], h0, acc, 0, 0, 0);
            acc = __builtin_amdgcn_mfma_f32_16x16x32_bf16(w3f[1], h1, acc, 0, 0, 0);
            float* op = out + (size_t)(t0 * 16 + c) * 9 + (g << 2);
            if (g < 2) {
                op[0] = eluf(acc[0]); op[1] = eluf(acc[1]);
                op[2] = eluf(acc[2]); op[3] = eluf(acc[3]);
            } else if (g == 2) {
                op[0] = eluf(acc[0]);   // dim 8
            }
        }
    }
}

// ---------------------------------------------------------------------------
// Fallback: round-1 fp32 fused kernel (only if ws too small)
// ---------------------------------------------------------------------------
__launch_bounds__(256, 2)
__global__ void fused_pca_mlp(const float* __restrict__ coords,
                              const float* __restrict__ distsq,
                              const float* __restrict__ feats,
                              const int*   __restrict__ nidx,
                              const float* __restrict__ W0, const float* __restrict__ b0,
                              const float* __restrict__ W1, const float* __restrict__ b1,
                              const float* __restrict__ W2, const float* __restrict__ b2,
                              const float* __restrict__ W3, const float* __restrict__ b3,
                              float* __restrict__ out)
{
    __shared__ __align__(16) float sW0t[64 * 9];
    __shared__ __align__(16) float sW1t[64 * 64];
    __shared__ __align__(16) float sW2t[64 * 64];
    __shared__ __align__(16) float sW3t[9 * 64];
    __shared__ float sB0[64], sB1[64], sB2[64], sB3[9];
    const int tid = threadIdx.x;
    for (int t = tid; t < 64 * 9; t += 256) { int j = t / 9, i = t - j * 9; sW0t[t] = W0[i * 64 + j]; }
    for (int t = tid; t < 64 * 64; t += 256) { int j = t >> 6, i = t & 63; sW1t[t] = W1[i * 64 + j]; }
    for (int t = tid; t < 64 * 64; t += 256) { int j = t >> 6, i = t & 63; sW2t[t] = W2[i * 64 + j]; }
    for (int t = tid; t < 9 * 64; t += 256) { int j = t >> 6, i = t & 63; sW3t[t] = W3[i * 9 + j]; }
    if (tid < 64) { sB0[tid] = b0[tid]; sB1[tid] = b1[tid]; sB2[tid] = b2[tid]; }
    if (tid < 9)  { sB3[tid] = b3[tid]; }
    __syncthreads();
    const int g = tid >> 4, f = tid & 15;
    const int v = blockIdx.x * 16 + g;
    if (v >= NV) return;
    const int* nix = nidx + (size_t)v * NK;
    const float* dsq = distsq + (size_t)v * NK;
    float s = 0.f, m0=0,m1=0,m2=0, q00=0,q01=0,q02=0,q11=0,q12=0,q22=0;
    #pragma unroll 4
    for (int k = 0; k < NK; ++k) {
        int idx = nix[k];
        float ew = __expf(-10.0f * dsq[k]);
        float w = feats[(size_t)idx * NF + f] * ew;
        float x = coords[(size_t)idx*3+0], y = coords[(size_t)idx*3+1], z = coords[(size_t)idx*3+2];
        s += w; m0 = fmaf(w,x,m0); m1 = fmaf(w,y,m1); m2 = fmaf(w,z,m2);
        float wx=w*x, wy=w*y, wz=w*z;
        q00=fmaf(wx,x,q00); q01=fmaf(wx,y,q01); q02=fmaf(wx,z,q02);
        q11=fmaf(wy,y,q11); q12=fmaf(wy,z,q12); q22=fmaf(wz,z,q22);
    }
    float inv = 1.0f/(s+EPS_W), mu0=m0*inv, mu1=m1*inv, mu2=m2*inv;
    float xr[9];
    xr[0]=fmaf(-mu0,mu0,q00*inv); xr[1]=fmaf(-mu0,mu1,q01*inv); xr[2]=fmaf(-mu0,mu2,q02*inv);
    xr[3]=xr[1]; xr[4]=fmaf(-mu1,mu1,q11*inv); xr[5]=fmaf(-mu1,mu2,q12*inv);
    xr[6]=xr[2]; xr[7]=xr[5]; xr[8]=fmaf(-mu2,mu2,q22*inv);
    float h[64], gg[64];
    #pragma unroll
    for (int j = 0; j < 64; ++j) {
        float aa = sB0[j]; const float* wr = sW0t + j * 9;
        #pragma unroll
        for (int i = 0; i < 9; ++i) aa = fmaf(xr[i], wr[i], aa);
        h[j] = eluf(aa);
    }
    #pragma unroll
    for (int j = 0; j < 64; ++j) {
        float aa = sB1[j]; const float4* wr = (const float4*)(sW1t + (j << 6));
        #pragma unroll
        for (int i4 = 0; i4 < 16; ++i4) { float4 wv = wr[i4];
            aa = fmaf(h[4*i4+0],wv.x,aa); aa = fmaf(h[4*i4+1],wv.y,aa);
            aa = fmaf(h[4*i4+2],wv.z,aa); aa = fmaf(h[4*i4+3],wv.w,aa); }
        gg[j] = eluf(aa);
    }
    #pragma unroll
    for (int j = 0; j < 64; ++j) {
        float aa = sB2[j]; const float4* wr = (const float4*)(sW2t + (j << 6));
        #pragma unroll
        for (int i4 = 0; i4 < 16; ++i4) { float4 wv = wr[i4];
            aa = fmaf(gg[4*i4+0],wv.x,aa); aa = fmaf(gg[4*i4+1],wv.y,aa);
            aa = fmaf(gg[4*i4+2],wv.z,aa); aa = fmaf(gg[4*i4+3],wv.w,aa); }
        h[j] = eluf(aa);
    }
    float o[9];
    #pragma unroll
    for (int j = 0; j < 9; ++j) {
        float aa = sB3[j]; const float4* wr = (const float4*)(sW3t + (j << 6));
        #pragma unroll
        for (int i4 = 0; i4 < 16; ++i4) { float4 wv = wr[i4];
            aa = fmaf(h[4*i4+0],wv.x,aa); aa = fmaf(h[4*i4+1],wv.y,aa);
            aa = fmaf(h[4*i4+2],wv.z,aa); aa = fmaf(h[4*i4+3],wv.w,aa); }
        o[j] = eluf(aa);
    }
    float* op = out + ((size_t)v * NF + f) * 9;
    #pragma unroll
    for (int j = 0; j < 9; ++j) op[j] = o[j];
}

extern "C" void kernel_launch(void* const* d_in, const int* in_sizes, int n_in,
                              void* d_out, int out_size, void* d_ws, size_t ws_size,
                              hipStream_t stream) {
    (void)in_sizes; (void)n_in; (void)out_size;
    const float* coords = (const float*)d_in[0];
    const float* distsq = (const float*)d_in[1];
    const float* feats  = (const float*)d_in[2];
    const int*   nidx   = (const int*)d_in[3];
    const float* W0 = (const float*)d_in[4];
    const float* b0 = (const float*)d_in[5];
    const float* W1 = (const float*)d_in[6];
    const float* b1 = (const float*)d_in[7];
    const float* W2 = (const float*)d_in[8];
    const float* b2 = (const float*)d_in[9];
    const float* W3 = (const float*)d_in[10];
    const float* b3 = (const float*)d_in[11];
    float* out = (float*)d_out;

    if (ws_size >= WS_NEED) {
        unsigned char* ws = (unsigned char*)d_ws;
        hipLaunchKernelGGL(cov2_kernel, dim3(NV / 16), dim3(256), 0, stream,
                           coords, distsq, feats, nidx, ws);
        hipLaunchKernelGGL(mlp_kernel, dim3(2048), dim3(256), 0, stream,
                           ws, W0, b0, W1, b1, W2, b2, W3, b3, out);
    } else {
        hipLaunchKernelGGL(fused_pca_mlp, dim3(NV / 16), dim3(256), 0, stream,
                           coords, distsq, feats, nidx,
                           W0, b0, W1, b1, W2, b2, W3, b3, out);
    }
}

// Round 5
// 200.727 us; speedup vs baseline: 1.7015x; 1.1804x over previous
//
#include <hip/hip_runtime.h>
#include <math.h>

#define NV 100000
#define NK 64
#define NF 16
#define EPS_W 1e-4f
#define WS_NEED ((size_t)NV * 16 * 32)   // 51.2 MB: [V*F=1.6M rows][16 bf16]

typedef __attribute__((ext_vector_type(8))) short bf16x8;
typedef __attribute__((ext_vector_type(4))) float f32x4;

__device__ __forceinline__ unsigned short bfu(float x) {
    return __builtin_bit_cast(unsigned short, (__bf16)x);   // HW RNE cvt
}
__device__ __forceinline__ unsigned int pk2(float lo, float hi) {
    return (unsigned int)bfu(lo) | ((unsigned int)bfu(hi) << 16);
}
__device__ __forceinline__ float eluf(float x) {
    return x > 0.f ? x : __expf(x) - 1.f;
}

// ---------------------------------------------------------------------------
// Kernel A: neighbour covariance (round-2 structure; known-good, ~81us)
// writes bf16 rows [v*16+f][16]: dims 0-8 cov, dim 9 = 1.0 (bias slot), rest 0
// ---------------------------------------------------------------------------
__launch_bounds__(256)
__global__ void cov_kernel(const float* __restrict__ coords,
                           const float* __restrict__ distsq,
                           const float* __restrict__ feats,
                           const int*   __restrict__ nidx,
                           unsigned char* __restrict__ ws)
{
    __shared__ float sEW[16][64];
    __shared__ int   sIX[16][64];
    const int tid = threadIdx.x;
    const int gv  = tid >> 4;          // vertex-in-block 0..15
    const int f   = tid & 15;          // feature 0..15
    const int v   = blockIdx.x * 16 + gv;

    {
        const size_t base = (size_t)v * NK + 4 * f;
        float4 d4 = *(const float4*)(distsq + base);
        int4   i4 = *(const int4*)(nidx + base);
        sEW[gv][4*f+0] = __expf(-10.f * d4.x);
        sEW[gv][4*f+1] = __expf(-10.f * d4.y);
        sEW[gv][4*f+2] = __expf(-10.f * d4.z);
        sEW[gv][4*f+3] = __expf(-10.f * d4.w);
        sIX[gv][4*f+0] = i4.x; sIX[gv][4*f+1] = i4.y;
        sIX[gv][4*f+2] = i4.z; sIX[gv][4*f+3] = i4.w;
    }
    __syncthreads();

    float s = 0.f, m0=0.f,m1=0.f,m2=0.f;
    float q00=0.f,q01=0.f,q02=0.f,q11=0.f,q12=0.f,q22=0.f;

    #pragma unroll 4
    for (int k = 0; k < NK; ++k) {
        int   idx = sIX[gv][k];
        float ew  = sEW[gv][k];
        float w   = feats[(size_t)idx * NF + f] * ew;
        float x = coords[(size_t)idx*3+0];
        float y = coords[(size_t)idx*3+1];
        float z = coords[(size_t)idx*3+2];
        s += w;
        m0 = fmaf(w,x,m0); m1 = fmaf(w,y,m1); m2 = fmaf(w,z,m2);
        float wx=w*x, wy=w*y, wz=w*z;
        q00=fmaf(wx,x,q00); q01=fmaf(wx,y,q01); q02=fmaf(wx,z,q02);
        q11=fmaf(wy,y,q11); q12=fmaf(wy,z,q12); q22=fmaf(wz,z,q22);
    }
    float inv = 1.f / (s + EPS_W);
    float mu0=m0*inv, mu1=m1*inv, mu2=m2*inv;
    float c00=fmaf(-mu0,mu0,q00*inv);
    float c01=fmaf(-mu0,mu1,q01*inv);
    float c02=fmaf(-mu0,mu2,q02*inv);
    float c11=fmaf(-mu1,mu1,q11*inv);
    float c12=fmaf(-mu1,mu2,q12*inv);
    float c22=fmaf(-mu2,mu2,q22*inv);

    uint4 lo, hi;
    lo.x = pk2(c00, c01);
    lo.y = pk2(c02, c01);
    lo.z = pk2(c11, c12);
    lo.w = pk2(c02, c12);
    hi.x = pk2(c22, 1.0f);
    hi.y = 0u; hi.z = 0u; hi.w = 0u;

    uint4* dst = (uint4*)(ws + ((size_t)v * 16 + f) * 32);
    dst[0] = lo;
    dst[1] = hi;
}

// ---------------------------------------------------------------------------
// Kernel B (mlp3): MFMA MLP, 2 vertices per wave-iteration (ILP=2),
// W1/W2 + biases in block-shared LDS (frees ~96 VGPRs -> more waves).
// D layout: col=lane&15, row=4*(lane>>4)+reg.  A/B: row/col=lane&15, k=8*(lane>>4)+i.
// sW layout: W^T bf16, elem (j,k) at byte (j*128 + 2k) ^ ((j&7)<<4).
// ---------------------------------------------------------------------------
__device__ __forceinline__ bf16x8 rdfrag(const short* hb, int c, int g, int kc) {
    int boff = ((kc << 6) + (g << 4)) ^ ((c & 7) << 4);
    return *(const bf16x8*)(hb + c * 64 + (boff >> 1));
}
__device__ __forceinline__ void wrH(short* hb, int c, int g, int t,
                                    unsigned int p01, unsigned int p23) {
    int boff = ((t << 5) + (g << 3)) ^ ((c & 7) << 4);
    uint2 val; val.x = p01; val.y = p23;
    *(uint2*)(hb + c * 64 + (boff >> 1)) = val;
}
__device__ __forceinline__ bf16x8 rdW(const short* sw, int c, int g, int t, int kc) {
    int byte = (t << 11) + (c << 7) + (kc << 6) + (g << 4);
    byte ^= (c & 7) << 4;
    return *(const bf16x8*)((const char*)sw + byte);
}

__launch_bounds__(256)
__global__ void mlp3_kernel(const unsigned char* __restrict__ ws,
                            const float* __restrict__ W0, const float* __restrict__ b0,
                            const float* __restrict__ W1, const float* __restrict__ b1,
                            const float* __restrict__ W2, const float* __restrict__ b2,
                            const float* __restrict__ W3, const float* __restrict__ b3,
                            float* __restrict__ out)
{
    __shared__ __align__(16) short sW1[4096];          // 8 KB swizzled W1^T
    __shared__ __align__(16) short sW2[4096];          // 8 KB swizzled W2^T
    __shared__ float sB1[64], sB2[64], sB3[16];
    __shared__ __align__(16) short hbuf[4][2][1024];   // [wave][vsel][16*64]

    const int tid  = threadIdx.x;
    const int wid  = tid >> 6;
    const int lane = tid & 63;
    const int c    = lane & 15;
    const int g    = lane >> 4;

    union U8 { short s[8]; bf16x8 v; };

    // ---- stage W1,W2 into swizzled LDS (2 tasks/thread each) ----
    #pragma unroll
    for (int r = 0; r < 2; ++r) {
        int t = tid + r * 256;          // task: j = t&63, k-oct o = t>>6
        int j = t & 63, o = t >> 6;
        U8 u1, u2;
        #pragma unroll
        for (int i = 0; i < 8; ++i) {
            u1.s[i] = (short)bfu(W1[(8 * o + i) * 64 + j]);
            u2.s[i] = (short)bfu(W2[(8 * o + i) * 64 + j]);
        }
        int byte = ((j << 7) + (o << 4)) ^ ((j & 7) << 4);
        *(bf16x8*)((char*)sW1 + byte) = u1.v;
        *(bf16x8*)((char*)sW2 + byte) = u2.v;
    }
    if (tid < 64) { sB1[tid] = b1[tid]; sB2[tid] = b2[tid]; }
    if (tid < 16) sB3[tid] = (tid < 9) ? b3[tid] : 0.f;
    __syncthreads();

    // ---- W0 / W3 fragments in VGPRs ----
    bf16x8 w0f[4], w3f[2];
    #pragma unroll
    for (int t = 0; t < 4; ++t) {
        U8 u;
        #pragma unroll
        for (int i = 0; i < 8; ++i) {
            int k = 8 * g + i;
            float val = 0.f;
            if (k < 9)       val = W0[k * 64 + 16 * t + c];
            else if (k == 9) val = b0[16 * t + c];       // bias via dim-9 = 1.0
            u.s[i] = (short)bfu(val);
        }
        w0f[t] = u.v;
    }
    #pragma unroll
    for (int kc = 0; kc < 2; ++kc) {
        U8 u;
        #pragma unroll
        for (int i = 0; i < 8; ++i) {
            int k = 32 * kc + 8 * g + i;
            u.s[i] = (short)bfu(c < 9 ? W3[k * 9 + c] : 0.f);
        }
        w3f[kc] = u.v;
    }

    short* hb0 = &hbuf[wid][0][0];
    short* hb1 = &hbuf[wid][1][0];

    // ---- pair loop: wave owns 2 vertices per iteration ----
    const int npair  = NV / 2;
    const int stride = gridDim.x * 4;
    for (int p = blockIdx.x * 4 + wid; p < npair; p += stride) {
        const int v0 = 2 * p, v1 = 2 * p + 1;
        f32x4 A0[4], A1[4];

        // ---- layer 0 ----
        {
            bf16x8 bin0 = *(const bf16x8*)(ws + (size_t)v0 * 512 + (c << 5) + ((g & 1) << 4));
            bf16x8 bin1 = *(const bf16x8*)(ws + (size_t)v1 * 512 + (c << 5) + ((g & 1) << 4));
            #pragma unroll
            for (int t = 0; t < 4; ++t) {
                f32x4 z4 = {0.f, 0.f, 0.f, 0.f};
                A0[t] = __builtin_amdgcn_mfma_f32_16x16x32_bf16(w0f[t], bin0, z4, 0, 0, 0);
                A1[t] = __builtin_amdgcn_mfma_f32_16x16x32_bf16(w0f[t], bin1, z4, 0, 0, 0);
            }
            #pragma unroll
            for (int t = 0; t < 4; ++t) {
                wrH(hb0, c, g, t, pk2(eluf(A0[t][0]), eluf(A0[t][1])),
                                  pk2(eluf(A0[t][2]), eluf(A0[t][3])));
                wrH(hb1, c, g, t, pk2(eluf(A1[t][0]), eluf(A1[t][1])),
                                  pk2(eluf(A1[t][2]), eluf(A1[t][3])));
            }
        }
        __asm__ volatile("s_waitcnt lgkmcnt(0)" ::: "memory");

        // ---- layer 1 ----
        {
            bf16x8 h00 = rdfrag(hb0, c, g, 0), h01 = rdfrag(hb0, c, g, 1);
            bf16x8 h10 = rdfrag(hb1, c, g, 0), h11 = rdfrag(hb1, c, g, 1);
            #pragma unroll
            for (int t = 0; t < 4; ++t) {
                bf16x8 wa = rdW(sW1, c, g, t, 0);
                bf16x8 wb = rdW(sW1, c, g, t, 1);
                f32x4 z4 = {0.f, 0.f, 0.f, 0.f};
                f32x4 a0 = __builtin_amdgcn_mfma_f32_16x16x32_bf16(wa, h00, z4, 0, 0, 0);
                a0       = __builtin_amdgcn_mfma_f32_16x16x32_bf16(wb, h01, a0, 0, 0, 0);
                f32x4 a1 = __builtin_amdgcn_mfma_f32_16x16x32_bf16(wa, h10, z4, 0, 0, 0);
                a1       = __builtin_amdgcn_mfma_f32_16x16x32_bf16(wb, h11, a1, 0, 0, 0);
                A0[t] = a0; A1[t] = a1;
            }
            #pragma unroll
            for (int t = 0; t < 4; ++t) {
                float4 bb = *(const float4*)(sB1 + 16 * t + 4 * g);
                wrH(hb0, c, g, t, pk2(eluf(A0[t][0] + bb.x), eluf(A0[t][1] + bb.y)),
                                  pk2(eluf(A0[t][2] + bb.z), eluf(A0[t][3] + bb.w)));
                wrH(hb1, c, g, t, pk2(eluf(A1[t][0] + bb.x), eluf(A1[t][1] + bb.y)),
                                  pk2(eluf(A1[t][2] + bb.z), eluf(A1[t][3] + bb.w)));
            }
        }
        __asm__ volatile("s_waitcnt lgkmcnt(0)" ::: "memory");

        // ---- layer 2 ----
        {
            bf16x8 h00 = rdfrag(hb0, c, g, 0), h01 = rdfrag(hb0, c, g, 1);
            bf16x8 h10 = rdfrag(hb1, c, g, 0), h11 = rdfrag(hb1, c, g, 1);
            #pragma unroll
            for (int t = 0; t < 4; ++t) {
                bf16x8 wa = rdW(sW2, c, g, t, 0);
                bf16x8 wb = rdW(sW2, c, g, t, 1);
                f32x4 z4 = {0.f, 0.f, 0.f, 0.f};
                f32x4 a0 = __builtin_amdgcn_mfma_f32_16x16x32_bf16(wa, h00, z4, 0, 0, 0);
                a0       = __builtin_amdgcn_mfma_f32_16x16x32_bf16(wb, h01, a0, 0, 0, 0);
                f32x4 a1 = __builtin_amdgcn_mfma_f32_16x16x32_bf16(wa, h10, z4, 0, 0, 0);
                a1       = __builtin_amdgcn_mfma_f32_16x16x32_bf16(wb, h11, a1, 0, 0, 0);
                A0[t] = a0; A1[t] = a1;
            }
            #pragma unroll
            for (int t = 0; t < 4; ++t) {
                float4 bb = *(const float4*)(sB2 + 16 * t + 4 * g);
                wrH(hb0, c, g, t, pk2(eluf(A0[t][0] + bb.x), eluf(A0[t][1] + bb.y)),
                                  pk2(eluf(A0[t][2] + bb.z), eluf(A0[t][3] + bb.w)));
                wrH(hb1, c, g, t, pk2(eluf(A1[t][0] + bb.x), eluf(A1[t][1] + bb.y)),
                                  pk2(eluf(A1[t][2] + bb.z), eluf(A1[t][3] + bb.w)));
            }
        }
        __asm__ volatile("s_waitcnt lgkmcnt(0)" ::: "memory");

        // ---- layer 3: 64 -> 9 ----
        {
            bf16x8 h00 = rdfrag(hb0, c, g, 0), h01 = rdfrag(hb0, c, g, 1);
            bf16x8 h10 = rdfrag(hb1, c, g, 0), h11 = rdfrag(hb1, c, g, 1);
            f32x4 z4 = {0.f, 0.f, 0.f, 0.f};
            f32x4 a0 = __builtin_amdgcn_mfma_f32_16x16x32_bf16(w3f[0], h00, z4, 0, 0, 0);
            a0       = __builtin_amdgcn_mfma_f32_16x16x32_bf16(w3f[1], h01, a0, 0, 0, 0);
            f32x4 a1 = __builtin_amdgcn_mfma_f32_16x16x32_bf16(w3f[0], h10, z4, 0, 0, 0);
            a1       = __builtin_amdgcn_mfma_f32_16x16x32_bf16(w3f[1], h11, a1, 0, 0, 0);
            float4 bb = *(const float4*)(sB3 + 4 * g);
            float* op0 = out + (size_t)(v0 * 16 + c) * 9 + (g << 2);
            float* op1 = out + (size_t)(v1 * 16 + c) * 9 + (g << 2);
            if (g < 2) {
                op0[0] = eluf(a0[0] + bb.x); op0[1] = eluf(a0[1] + bb.y);
                op0[2] = eluf(a0[2] + bb.z); op0[3] = eluf(a0[3] + bb.w);
                op1[0] = eluf(a1[0] + bb.x); op1[1] = eluf(a1[1] + bb.y);
                op1[2] = eluf(a1[2] + bb.z); op1[3] = eluf(a1[3] + bb.w);
            } else if (g == 2) {
                op0[0] = eluf(a0[0] + bb.x);
                op1[0] = eluf(a1[0] + bb.x);
            }
        }
    }
}

// ---------------------------------------------------------------------------
// Fallback: round-1 fp32 fused kernel (only if ws too small)
// ---------------------------------------------------------------------------
__launch_bounds__(256, 2)
__global__ void fused_pca_mlp(const float* __restrict__ coords,
                              const float* __restrict__ distsq,
                              const float* __restrict__ feats,
                              const int*   __restrict__ nidx,
                              const float* __restrict__ W0, const float* __restrict__ b0,
                              const float* __restrict__ W1, const float* __restrict__ b1,
                              const float* __restrict__ W2, const float* __restrict__ b2,
                              const float* __restrict__ W3, const float* __restrict__ b3,
                              float* __restrict__ out)
{
    __shared__ __align__(16) float sW0t[64 * 9];
    __shared__ __align__(16) float sW1t[64 * 64];
    __shared__ __align__(16) float sW2t[64 * 64];
    __shared__ __align__(16) float sW3t[9 * 64];
    __shared__ float sB0[64], sB1[64], sB2[64], sB3[9];
    const int tid = threadIdx.x;
    for (int t = tid; t < 64 * 9; t += 256) { int j = t / 9, i = t - j * 9; sW0t[t] = W0[i * 64 + j]; }
    for (int t = tid; t < 64 * 64; t += 256) { int j = t >> 6, i = t & 63; sW1t[t] = W1[i * 64 + j]; }
    for (int t = tid; t < 64 * 64; t += 256) { int j = t >> 6, i = t & 63; sW2t[t] = W2[i * 64 + j]; }
    for (int t = tid; t < 9 * 64; t += 256) { int j = t >> 6, i = t & 63; sW3t[t] = W3[i * 9 + j]; }
    if (tid < 64) { sB0[tid] = b0[tid]; sB1[tid] = b1[tid]; sB2[tid] = b2[tid]; }
    if (tid < 9)  { sB3[tid] = b3[tid]; }
    __syncthreads();
    const int g = tid >> 4, f = tid & 15;
    const int v = blockIdx.x * 16 + g;
    if (v >= NV) return;
    const int* nix = nidx + (size_t)v * NK;
    const float* dsq = distsq + (size_t)v * NK;
    float s = 0.f, m0=0,m1=0,m2=0, q00=0,q01=0,q02=0,q11=0,q12=0,q22=0;
    #pragma unroll 4
    for (int k = 0; k < NK; ++k) {
        int idx = nix[k];
        float ew = __expf(-10.0f * dsq[k]);
        float w = feats[(size_t)idx * NF + f] * ew;
        float x = coords[(size_t)idx*3+0], y = coords[(size_t)idx*3+1], z = coords[(size_t)idx*3+2];
        s += w; m0 = fmaf(w,x,m0); m1 = fmaf(w,y,m1); m2 = fmaf(w,z,m2);
        float wx=w*x, wy=w*y, wz=w*z;
        q00=fmaf(wx,x,q00); q01=fmaf(wx,y,q01); q02=fmaf(wx,z,q02);
        q11=fmaf(wy,y,q11); q12=fmaf(wy,z,q12); q22=fmaf(wz,z,q22);
    }
    float inv = 1.0f/(s+EPS_W), mu0=m0*inv, mu1=m1*inv, mu2=m2*inv;
    float xr[9];
    xr[0]=fmaf(-mu0,mu0,q00*inv); xr[1]=fmaf(-mu0,mu1,q01*inv); xr[2]=fmaf(-mu0,mu2,q02*inv);
    xr[3]=xr[1]; xr[4]=fmaf(-mu1,mu1,q11*inv); xr[5]=fmaf(-mu1,mu2,q12*inv);
    xr[6]=xr[2]; xr[7]=xr[5]; xr[8]=fmaf(-mu2,mu2,q22*inv);
    float h[64], gg[64];
    #pragma unroll
    for (int j = 0; j < 64; ++j) {
        float aa = sB0[j]; const float* wr = sW0t + j * 9;
        #pragma unroll
        for (int i = 0; i < 9; ++i) aa = fmaf(xr[i], wr[i], aa);
        h[j] = eluf(aa);
    }
    #pragma unroll
    for (int j = 0; j < 64; ++j) {
        float aa = sB1[j]; const float4* wr = (const float4*)(sW1t + (j << 6));
        #pragma unroll
        for (int i4 = 0; i4 < 16; ++i4) { float4 wv = wr[i4];
            aa = fmaf(h[4*i4+0],wv.x,aa); aa = fmaf(h[4*i4+1],wv.y,aa);
            aa = fmaf(h[4*i4+2],wv.z,aa); aa = fmaf(h[4*i4+3],wv.w,aa); }
        gg[j] = eluf(aa);
    }
    #pragma unroll
    for (int j = 0; j < 64; ++j) {
        float aa = sB2[j]; const float4* wr = (const float4*)(sW2t + (j << 6));
        #pragma unroll
        for (int i4 = 0; i4 < 16; ++i4) { float4 wv = wr[i4];
            aa = fmaf(gg[4*i4+0],wv.x,aa); aa = fmaf(gg[4*i4+1],wv.y,aa);
            aa = fmaf(gg[4*i4+2],wv.z,aa); aa = fmaf(gg[4*i4+3],wv.w,aa); }
        h[j] = eluf(aa);
    }
    float o[9];
    #pragma unroll
    for (int j = 0; j < 9; ++j) {
        float aa = sB3[j]; const float4* wr = (const float4*)(sW3t + (j << 6));
        #pragma unroll
        for (int i4 = 0; i4 < 16; ++i4) { float4 wv = wr[i4];
            aa = fmaf(h[4*i4+0],wv.x,aa); aa = fmaf(h[4*i4+1],wv.y,aa);
            aa = fmaf(h[4*i4+2],wv.z,aa); aa = fmaf(h[4*i4+3],wv.w,aa); }
        o[j] = eluf(aa);
    }
    float* op = out + ((size_t)v * NF + f) * 9;
    #pragma unroll
    for (int j = 0; j < 9; ++j) op[j] = o[j];
}

extern "C" void kernel_launch(void* const* d_in, const int* in_sizes, int n_in,
                              void* d_out, int out_size, void* d_ws, size_t ws_size,
                              hipStream_t stream) {
    (void)in_sizes; (void)n_in; (void)out_size;
    const float* coords = (const float*)d_in[0];
    const float* distsq = (const float*)d_in[1];
    const float* feats  = (const float*)d_in[2];
    const int*   nidx   = (const int*)d_in[3];
    const float* W0 = (const float*)d_in[4];
    const float* b0 = (const float*)d_in[5];
    const float* W1 = (const float*)d_in[6];
    const float* b1 = (const float*)d_in[7];
    const float* W2 = (const float*)d_in[8];
    const float* b2 = (const float*)d_in[9];
    const float* W3 = (const float*)d_in[10];
    const float* b3 = (const float*)d_in[11];
    float* out = (float*)d_out;

    if (ws_size >= WS_NEED) {
        unsigned char* ws = (unsigned char*)d_ws;
        hipLaunchKernelGGL(cov_kernel, dim3(NV / 16), dim3(256), 0, stream,
                           coords, distsq, feats, nidx, ws);
        hipLaunchKernelGGL(mlp3_kernel, dim3(2048), dim3(256), 0, stream,
                           ws, W0, b0, W1, b1, W2, b2, W3, b3, out);
    } else {
        hipLaunchKernelGGL(fused_pca_mlp, dim3(NV / 16), dim3(256), 0, stream,
                           coords, distsq, feats, nidx,
                           W0, b0, W1, b1, W2, b2, W3, b3, out);
    }
}